// Round 3
// baseline (627.251 us; speedup 1.0000x reference)
//
#include <hip/hip_runtime.h>
#include <hip/hip_bf16.h>

typedef unsigned short ushort_t;
typedef __attribute__((ext_vector_type(4))) float f32x4;
typedef __attribute__((ext_vector_type(8))) short bf16x8;
typedef __attribute__((ext_vector_type(8))) unsigned short us8;

#define T_TOK 4096
#define D_DIM 1024
#define FF_DIM 4096
#define NE 8
#define ESTRIDE 4194304L  // 4096*1024 elements per expert weight matrix

__device__ __forceinline__ unsigned short f2bf(float f) {
  __hip_bfloat16 h = __float2bfloat16(f);
  return __builtin_bit_cast(unsigned short, h);
}
__device__ __forceinline__ float gelu_f(float v) {
  return 0.5f * v * (1.0f + erff(v * 0.70710678118654752440f));
}

// ---------------- gating: logits -> softmax top2 -> expert lists -------------
__global__ void gate_kernel(const float* __restrict__ x, const float* __restrict__ Wg,
                            int* __restrict__ cnt, int* __restrict__ tok,
                            float* __restrict__ wof, int* __restrict__ rankof) {
  const int t = blockIdx.x;
  const int lane = threadIdx.x;  // 64 threads = 1 wave
  const float* xr = x + (long)t * D_DIM;
  float acc[NE];
#pragma unroll
  for (int e = 0; e < NE; e++) acc[e] = 0.f;
#pragma unroll
  for (int i = 0; i < 16; i++) {
    int d = i * 64 + lane;
    float xv = xr[d];
    const float* wr = Wg + d * NE;
#pragma unroll
    for (int e = 0; e < NE; e++) acc[e] += xv * wr[e];
  }
#pragma unroll
  for (int off = 32; off > 0; off >>= 1) {
#pragma unroll
    for (int e = 0; e < NE; e++) acc[e] += __shfl_xor(acc[e], off, 64);
  }
  if (lane == 0) {
    int i0 = 0;
#pragma unroll
    for (int e = 1; e < NE; e++) if (acc[e] > acc[i0]) i0 = e;  // first max (ties -> low idx)
    int i1 = -1;
#pragma unroll
    for (int e = 0; e < NE; e++) {
      if (e == i0) continue;
      if (i1 < 0 || acc[e] > acc[i1]) i1 = e;
    }
    float e1 = expf(acc[i1] - acc[i0]);
    float w0 = 1.f / (1.f + e1);
    float w1 = e1 * w0;
    int s0 = atomicAdd(&cnt[i0], 1);
    tok[i0 * T_TOK + s0] = t; wof[i0 * T_TOK + s0] = w0; rankof[i0 * T_TOK + s0] = 0;
    int s1 = atomicAdd(&cnt[i1], 1);
    tok[i1 * T_TOK + s1] = t; wof[i1 * T_TOK + s1] = w1; rankof[i1 * T_TOK + s1] = 1;
    tok[8 * T_TOK + t] = t; wof[8 * T_TOK + t] = 1.f; rankof[8 * T_TOK + t] = 0;
  }
}

__global__ void scan_kernel(int* cnt, int* base) {
  if (threadIdx.x == 0 && blockIdx.x == 0) {
    int s = 0;
    for (int e = 0; e < NE; e++) { base[e] = s; s += cnt[e]; }
    base[8] = s;      // always 8192
    cnt[8] = T_TOK;   // shared pseudo-expert gets all tokens
  }
}

// ---------------- fp32 -> bf16 convert (x) ----------------------------------
__global__ void cvt_x_kernel(const float* __restrict__ src, ushort_t* __restrict__ dst) {
  long i = ((long)blockIdx.x * 256 + threadIdx.x) * 8;
  float4 v0 = *(const float4*)(src + i);
  float4 v1 = *(const float4*)(src + i + 4);
  us8 o;
  o[0] = f2bf(v0.x); o[1] = f2bf(v0.y); o[2] = f2bf(v0.z); o[3] = f2bf(v0.w);
  o[4] = f2bf(v1.x); o[5] = f2bf(v1.y); o[6] = f2bf(v1.z); o[7] = f2bf(v1.w);
  *(us8*)(dst + i) = o;
}

// ---------------- fp32 [R][C] -> bf16 [C][R] transpose-convert --------------
__global__ void tcvt_kernel(const float* __restrict__ src, ushort_t* __restrict__ dst,
                            int R, int C) {
  src += (long)blockIdx.z * R * C;
  dst += (long)blockIdx.z * R * C;
  const int r0 = blockIdx.y * 64, c0 = blockIdx.x * 64;
  __shared__ ushort_t tile[64][72];
  const int t = threadIdx.x;
#pragma unroll
  for (int i = 0; i < 4; i++) {
    int lin = t + i * 256;
    int r = lin >> 4;
    int c = (lin & 15) * 4;
    float4 v = *(const float4*)(src + (long)(r0 + r) * C + c0 + c);
    tile[c + 0][r] = f2bf(v.x);
    tile[c + 1][r] = f2bf(v.y);
    tile[c + 2][r] = f2bf(v.z);
    tile[c + 3][r] = f2bf(v.w);
  }
  __syncthreads();
#pragma unroll
  for (int i = 0; i < 2; i++) {
    int lin = t + i * 256;
    int cc = lin >> 3, rp = lin & 7;
    us8 v = *(const us8*)&tile[cc][rp * 8];
    *(us8*)(dst + (long)(c0 + cc) * R + r0 + rp * 8) = v;
  }
}

// ---------------- GEMM: 256x256 tile, 8 waves (2x4), BK=32, counted vmcnt ----
// 16 LDS slots x 8KB; K-tile t = chunks 4t..4t+3 (A rows 0-127 / 128-255,
// B cols 0-127 / 128-255), slot = chunk & 15. Chunks staged 2 tiles ahead,
// 1 global_load_lds (16B/lane) per thread per chunk. Tile boundary:
// s_waitcnt vmcnt(4) + raw s_barrier -> confirms this tile's 4 chunks, keeps
// 4 loads in flight (never drains until the last tile).
// LDS swizzle: data (r, kc) stored at 16B-slot kc ^ ((r>>1)&3) within the
// row (inverse applied on the per-lane GLOBAL source; LDS dest stays linear).
// PHASE 1: He = gelu(gather(Xbf) @ W1T^T + b1)   (K=1024, N=4096)
// PHASE 2: ybuf/out = route(He @ W2T^T + b2)     (K=4096, N=1024)
template <int K, int N, int PHASE>
__global__ __launch_bounds__(512, 2) void gemm_kernel(
    const ushort_t* __restrict__ Abase, const ushort_t* __restrict__ WT,
    const float* __restrict__ bias_e, const float* __restrict__ bias_s,
    const int* __restrict__ cnt, const int* __restrict__ base,
    const int* __restrict__ tok, const float* __restrict__ wof,
    const int* __restrict__ rankof,
    ushort_t* __restrict__ He, float* __restrict__ ybuf, float* __restrict__ out) {
  const int e = blockIdx.z;
  const int count = cnt[e];
  const int m0 = blockIdx.y * 256;
  if (m0 >= count) return;  // uniform early-exit before any barrier
  const int n0 = blockIdx.x * 256;
  const int tid = threadIdx.x;
  const int w = tid >> 6, lane = tid & 63;
  const int wm = w >> 2, wn = w & 3;  // 2x4 wave grid; wave owns 128x64 out
  const int lr = lane & 15, lg = lane >> 4;

  __shared__ ushort_t lds_u[16 * 4096];  // 16 slots x 8 KiB = 128 KiB
  char* const lds = (char*)lds_u;

  constexpr int NT = K / 32;

  // ---- staging source (per thread; 1 x 16B load per chunk) ----
  // linear LDS pos o16 = tid: row r = tid>>2, stored slot kcs = tid&3,
  // global k-chunk = kcs ^ ((r>>1)&3)  [inverse swizzle on source]
  const int srow = tid >> 2;
  const int kcg = (tid & 3) ^ ((tid >> 3) & 3);
  const ushort_t* bsrc[4];
#pragma unroll
  for (int c = 0; c < 2; c++) {  // A chunks: block rows m0 + c*128 + srow
    int rr = m0 + c * 128 + srow;
    int rc = (rr < count) ? rr : 0;  // clamp OOB rows to a valid row
    long arow;
    if (PHASE == 1) arow = tok[e * T_TOK + rc];
    else            arow = (long)base[e] + rc;
    bsrc[c] = Abase + arow * (long)K + kcg * 8;
  }
#pragma unroll
  for (int c = 0; c < 2; c++) {  // B chunks: weight rows n0 + c*128 + srow
    long brow = n0 + c * 128 + srow;
    bsrc[2 + c] = WT + (long)e * ESTRIDE + brow * (long)K + kcg * 8;
  }

#define STAGE(g_, c_, tg_)                                                     \
  __builtin_amdgcn_global_load_lds(                                            \
      (const __attribute__((address_space(1))) void*)(bsrc[c_] + (long)(tg_) * 32), \
      (__attribute__((address_space(3))) void*)(lds + ((g_) & 15) * 8192 + w * 1024), \
      16, 0, 0)

  // ---- swizzled ds_read byte offsets (constant per thread) ----
  int offA[8], offB[4];
#pragma unroll
  for (int m = 0; m < 8; m++) {
    int r = m * 16 + lr;  // row within A chunk wm
    offA[m] = r * 64 + ((lg ^ ((r >> 1) & 3)) << 4);
  }
#pragma unroll
  for (int n = 0; n < 4; n++) {
    int r = (wn & 1) * 64 + n * 16 + lr;  // row within B chunk (wn>>1)
    offB[n] = r * 64 + ((lg ^ ((r >> 1) & 3)) << 4);
  }

  f32x4 acc[8][4] = {};

  // prologue: stage tiles 0 and 1 (chunks 0..7)
#pragma unroll
  for (int g = 0; g < 8; g++) STAGE(g, g & 3, g >> 2);

  int sA = wm;                // slot of A chunk (4t+wm) at t=0
  int sB = 2 + (wn >> 1);     // slot of B chunk (4t+2+(wn>>1)) at t=0

  for (int t = 0; t < NT; t++) {
    if (t == NT - 1) { asm volatile("s_waitcnt vmcnt(0)" ::: "memory"); }
    else             { asm volatile("s_waitcnt vmcnt(4)" ::: "memory"); }
    __builtin_amdgcn_s_barrier();
    asm volatile("" ::: "memory");  // no LDS access moves across the barrier

    const char* pa = lds + sA * 8192;
    const char* pb = lds + sB * 8192;

    // phase 0: stage A chunks of tile t+2; read A frags + B frags 0,1
    if (t + 2 < NT) { STAGE(4 * t + 8, 0, t + 2); STAGE(4 * t + 9, 1, t + 2); }
    bf16x8 av[8];
#pragma unroll
    for (int m = 0; m < 8; m++) av[m] = *(const bf16x8*)(pa + offA[m]);
    bf16x8 bv0 = *(const bf16x8*)(pb + offB[0]);
    bf16x8 bv1 = *(const bf16x8*)(pb + offB[1]);
    __builtin_amdgcn_s_setprio(1);
#pragma unroll
    for (int m = 0; m < 8; m++) {
      acc[m][0] = __builtin_amdgcn_mfma_f32_16x16x32_bf16(av[m], bv0, acc[m][0], 0, 0, 0);
      acc[m][1] = __builtin_amdgcn_mfma_f32_16x16x32_bf16(av[m], bv1, acc[m][1], 0, 0, 0);
    }
    __builtin_amdgcn_s_setprio(0);

    // phase 1: stage B chunks of tile t+2; read B frags 2,3
    if (t + 2 < NT) { STAGE(4 * t + 10, 2, t + 2); STAGE(4 * t + 11, 3, t + 2); }
    bf16x8 bv2 = *(const bf16x8*)(pb + offB[2]);
    bf16x8 bv3 = *(const bf16x8*)(pb + offB[3]);
    __builtin_amdgcn_s_setprio(1);
#pragma unroll
    for (int m = 0; m < 8; m++) {
      acc[m][2] = __builtin_amdgcn_mfma_f32_16x16x32_bf16(av[m], bv2, acc[m][2], 0, 0, 0);
      acc[m][3] = __builtin_amdgcn_mfma_f32_16x16x32_bf16(av[m], bv3, acc[m][3], 0, 0, 0);
    }
    __builtin_amdgcn_s_setprio(0);

    sA = (sA + 4) & 15;
    sB = (sB + 4) & 15;
  }
#undef STAGE

  const float* bias = (e == NE) ? bias_s : (bias_e + (long)e * N);
#pragma unroll
  for (int m = 0; m < 8; m++) {
#pragma unroll
    for (int j = 0; j < 4; j++) {
      int rloc = wm * 128 + m * 16 + lg * 4 + j;  // D row = (lane>>4)*4 + reg
      int rr = m0 + rloc;
      if (rr >= count) continue;
      if (PHASE == 1) {
        long orow = (long)base[e] + rr;
#pragma unroll
        for (int n = 0; n < 4; n++) {
          int col = n0 + wn * 64 + n * 16 + lr;  // D col = lane&15
          float v = acc[m][n][j] + bias[col];
          He[orow * FF_DIM + col] = f2bf(gelu_f(v));
        }
      } else {
        int tt = tok[e * T_TOK + rr];
        if (e == NE) {  // shared FFN -> write d_out directly
#pragma unroll
          for (int n = 0; n < 4; n++) {
            int col = n0 + wn * 64 + n * 16 + lr;
            out[(long)tt * D_DIM + col] = acc[m][n][j] + bias[col];
          }
        } else {
          float wgt = wof[e * T_TOK + rr];
          int rk = rankof[e * T_TOK + rr];
          float* dst = ybuf + (long)rk * ((long)T_TOK * D_DIM) + (long)tt * D_DIM;
#pragma unroll
          for (int n = 0; n < 4; n++) {
            int col = n0 + wn * 64 + n * 16 + lr;
            dst[col] = wgt * (acc[m][n][j] + bias[col]);
          }
        }
      }
    }
  }
}

// ---------------- final: out += y_rank0 + y_rank1 ---------------------------
__global__ void final_add_kernel(float* __restrict__ out, const float* __restrict__ ybuf) {
  long i = ((long)blockIdx.x * 256 + threadIdx.x) * 4;
  float4 a = *(const float4*)(out + i);
  float4 b = *(const float4*)(ybuf + i);
  float4 c = *(const float4*)(ybuf + (long)T_TOK * D_DIM + i);
  a.x += b.x + c.x; a.y += b.y + c.y; a.z += b.z + c.z; a.w += b.w + c.w;
  *(float4*)(out + i) = a;
}

extern "C" void kernel_launch(void* const* d_in, const int* in_sizes, int n_in,
                              void* d_out, int out_size, void* d_ws, size_t ws_size,
                              hipStream_t stream) {
  (void)in_sizes; (void)n_in; (void)out_size; (void)ws_size;
  const float* x   = (const float*)d_in[0];
  const float* Wg  = (const float*)d_in[1];
  const float* W1  = (const float*)d_in[2];
  const float* b1  = (const float*)d_in[3];
  const float* W2  = (const float*)d_in[4];
  const float* b2  = (const float*)d_in[5];
  const float* Ws1 = (const float*)d_in[6];
  const float* bs1 = (const float*)d_in[7];
  const float* Ws2 = (const float*)d_in[8];
  const float* bs2 = (const float*)d_in[9];
  float* out = (float*)d_out;

  char* ws = (char*)d_ws;
  int*      cnt    = (int*)(ws + 0);
  int*      base   = (int*)(ws + 64);
  int*      tok    = (int*)(ws + 256);
  float*    wof    = (float*)(ws + 256 + 147456);
  int*      rankof = (int*)(ws + 256 + 2 * 147456);
  ushort_t* Xbf    = (ushort_t*)(ws + 442624);
  ushort_t* W1T    = (ushort_t*)(ws + 8831232);
  ushort_t* W2T    = (ushort_t*)(ws + 84328704);
  ushort_t* He     = (ushort_t*)(ws + 159826176);
  float*    ybuf   = (float*)(ws + 261538048);

  hipMemsetAsync(cnt, 0, 64, stream);
  gate_kernel<<<T_TOK, 64, 0, stream>>>(x, Wg, cnt, tok, wof, rankof);
  scan_kernel<<<1, 64, 0, stream>>>(cnt, base);
  cvt_x_kernel<<<2048, 256, 0, stream>>>(x, Xbf);
  tcvt_kernel<<<dim3(64, 16, 8), 256, 0, stream>>>(W1, W1T, 1024, 4096);
  tcvt_kernel<<<dim3(16, 64, 8), 256, 0, stream>>>(W2, W2T, 4096, 1024);
  tcvt_kernel<<<dim3(64, 16, 1), 256, 0, stream>>>(Ws1, W1T + 8L * ESTRIDE, 1024, 4096);
  tcvt_kernel<<<dim3(16, 64, 1), 256, 0, stream>>>(Ws2, W2T + 8L * ESTRIDE, 4096, 1024);
  gemm_kernel<1024, 4096, 1><<<dim3(16, 16, 9), 512, 0, stream>>>(
      Xbf, W1T, b1, bs1, cnt, base, tok, wof, rankof, He, ybuf, out);
  gemm_kernel<4096, 1024, 2><<<dim3(4, 16, 9), 512, 0, stream>>>(
      He, W2T, b2, bs2, cnt, base, tok, wof, rankof, He, ybuf, out);
  final_add_kernel<<<4096, 256, 0, stream>>>(out, ybuf);
}

// Round 4
// 625.932 us; speedup vs baseline: 1.0021x; 1.0021x over previous
//
#include <hip/hip_runtime.h>
#include <hip/hip_bf16.h>

typedef unsigned short ushort_t;
typedef __attribute__((ext_vector_type(4))) float f32x4;
typedef __attribute__((ext_vector_type(8))) short bf16x8;
typedef __attribute__((ext_vector_type(8))) unsigned short us8;

#define T_TOK 4096
#define D_DIM 1024
#define FF_DIM 4096
#define NE 8
#define ESTRIDE 4194304L  // 4096*1024 elements per expert weight matrix

__device__ __forceinline__ unsigned short f2bf(float f) {
  __hip_bfloat16 h = __float2bfloat16(f);
  return __builtin_bit_cast(unsigned short, h);
}
__device__ __forceinline__ float gelu_f(float v) {
  return 0.5f * v * (1.0f + erff(v * 0.70710678118654752440f));
}

// ---------------- gating: logits -> softmax top2 -> expert lists -------------
__global__ void gate_kernel(const float* __restrict__ x, const float* __restrict__ Wg,
                            int* __restrict__ cnt, int* __restrict__ tok,
                            float* __restrict__ wof, int* __restrict__ rankof) {
  const int t = blockIdx.x;
  const int lane = threadIdx.x;  // 64 threads = 1 wave
  const float* xr = x + (long)t * D_DIM;
  float acc[NE];
#pragma unroll
  for (int e = 0; e < NE; e++) acc[e] = 0.f;
#pragma unroll
  for (int i = 0; i < 16; i++) {
    int d = i * 64 + lane;
    float xv = xr[d];
    const float* wr = Wg + d * NE;
#pragma unroll
    for (int e = 0; e < NE; e++) acc[e] += xv * wr[e];
  }
#pragma unroll
  for (int off = 32; off > 0; off >>= 1) {
#pragma unroll
    for (int e = 0; e < NE; e++) acc[e] += __shfl_xor(acc[e], off, 64);
  }
  if (lane == 0) {
    int i0 = 0;
#pragma unroll
    for (int e = 1; e < NE; e++) if (acc[e] > acc[i0]) i0 = e;
    int i1 = -1;
#pragma unroll
    for (int e = 0; e < NE; e++) {
      if (e == i0) continue;
      if (i1 < 0 || acc[e] > acc[i1]) i1 = e;
    }
    float e1 = expf(acc[i1] - acc[i0]);
    float w0 = 1.f / (1.f + e1);
    float w1 = e1 * w0;
    int s0 = atomicAdd(&cnt[i0], 1);
    tok[i0 * T_TOK + s0] = t; wof[i0 * T_TOK + s0] = w0; rankof[i0 * T_TOK + s0] = 0;
    int s1 = atomicAdd(&cnt[i1], 1);
    tok[i1 * T_TOK + s1] = t; wof[i1 * T_TOK + s1] = w1; rankof[i1 * T_TOK + s1] = 1;
    tok[8 * T_TOK + t] = t; wof[8 * T_TOK + t] = 1.f; rankof[8 * T_TOK + t] = 0;
  }
}

__global__ void scan_kernel(int* cnt, int* base) {
  if (threadIdx.x == 0 && blockIdx.x == 0) {
    int s = 0;
    for (int e = 0; e < NE; e++) { base[e] = s; s += cnt[e]; }
    base[8] = s;      // always 8192
    cnt[8] = T_TOK;   // shared pseudo-expert gets all tokens
  }
}

// ---------------- fp32 -> bf16 convert (x) ----------------------------------
__global__ void cvt_x_kernel(const float* __restrict__ src, ushort_t* __restrict__ dst) {
  long i = ((long)blockIdx.x * 256 + threadIdx.x) * 8;
  float4 v0 = *(const float4*)(src + i);
  float4 v1 = *(const float4*)(src + i + 4);
  us8 o;
  o[0] = f2bf(v0.x); o[1] = f2bf(v0.y); o[2] = f2bf(v0.z); o[3] = f2bf(v0.w);
  o[4] = f2bf(v1.x); o[5] = f2bf(v1.y); o[6] = f2bf(v1.z); o[7] = f2bf(v1.w);
  *(us8*)(dst + i) = o;
}

// ---------------- fp32 [R][C] -> bf16 [C][R] transpose-convert --------------
__global__ void tcvt_kernel(const float* __restrict__ src, ushort_t* __restrict__ dst,
                            int R, int C) {
  src += (long)blockIdx.z * R * C;
  dst += (long)blockIdx.z * R * C;
  const int r0 = blockIdx.y * 64, c0 = blockIdx.x * 64;
  __shared__ ushort_t tile[64][72];
  const int t = threadIdx.x;
#pragma unroll
  for (int i = 0; i < 4; i++) {
    int lin = t + i * 256;
    int r = lin >> 4;
    int c = (lin & 15) * 4;
    float4 v = *(const float4*)(src + (long)(r0 + r) * C + c0 + c);
    tile[c + 0][r] = f2bf(v.x);
    tile[c + 1][r] = f2bf(v.y);
    tile[c + 2][r] = f2bf(v.z);
    tile[c + 3][r] = f2bf(v.w);
  }
  __syncthreads();
#pragma unroll
  for (int i = 0; i < 2; i++) {
    int lin = t + i * 256;
    int cc = lin >> 3, rp = lin & 7;
    us8 v = *(const us8*)&tile[cc][rp * 8];
    *(us8*)(dst + (long)(c0 + cc) * R + r0 + rp * 8) = v;
  }
}

// ---------------- GEMM: 256x256 tile, 8 waves (2x4), BK=64, 8-phase ---------
// m201-template port. LDS: 2 dbuf x {A-half0, A-half1, B-half0, B-half1} x
// 16KB = 128 KiB. Each half = 2 kk-subtiles of [128 rows][64 B]; read swizzle
// slot = lg ^ ((r>>1)&3) (r3-proven, 0 bank conflicts); inverse swizzle applied
// on per-lane GLOBAL source, LDS stays linear (rule #21).
// Per K-tile t (4 phases, 2 raw barriers each):
//  P0: ds av(mh0) 8 + bvA(nh0) 4 | stage A1(t+1) | bar | lgkm0 | 16 MFMA Q00 | bar
//  P1: ds bvB(nh1) 4             | stage B1(t+1) | bar | lgkm0 | 16 MFMA Q01 | bar
//  P2: ds av(mh1) 8              | stage B0(t+2) | bar | lgkm0 | 16 MFMA Q10 | bar
//  P3: (no ds)                   | stage A0(t+2) | bar | lgkm0 | 16 MFMA Q11 |
//      boundary: vmcnt(4) (vmcnt(0) before last tile) | bar
// Ledger: prologue stages {B0,A0,A1,B1}(0),{B0,A0}(1); at every boundary the
// 2 newest stages (4 loads) may fly, everything older confirmed -> vmcnt(4).
// Every stage targets a dead region (last reader's lgkm-drain is >=1 barrier
// before the stage issue).
template <int K, int N, int PHASE>
__global__ __launch_bounds__(512, 2) void gemm_kernel(
    const ushort_t* __restrict__ Abase, const ushort_t* __restrict__ WT,
    const float* __restrict__ bias_e, const float* __restrict__ bias_s,
    const int* __restrict__ cnt, const int* __restrict__ base,
    const int* __restrict__ tok, const float* __restrict__ wof,
    const int* __restrict__ rankof,
    ushort_t* __restrict__ He, float* __restrict__ ybuf, float* __restrict__ out) {
  const int e = blockIdx.z;
  const int count = cnt[e];
  const int m0 = blockIdx.y * 256;
  if (m0 >= count) return;  // uniform early-exit before any barrier
  const int n0 = blockIdx.x * 256;
  const int tid = threadIdx.x;
  const int w = tid >> 6, lane = tid & 63;
  const int wm = w >> 2, wn = w & 3;  // 2x4 wave grid; wave owns 128x64 out
  const int lr = lane & 15, lg = lane >> 4;
  const int swk = ((lg ^ ((lr >> 1) & 3)) << 4);  // read-side swizzle byte off

  __shared__ ushort_t lds_u[2 * 32768];  // 128 KiB
  char* const lds = (char*)lds_u;

  constexpr int NT = K / 64;

  // ---- staging sources: thread t covers row sr2 = t>>2 of each half, global
  // 8-elem k-chunk kc2 = (t&3)^((t>>3)&3) (inverse swizzle); j in {0,1} covers
  // kk-subtiles (+32 elems). One pointer per half.
  const int sr2 = tid >> 2;
  const int kc2 = (tid & 3) ^ ((tid >> 3) & 3);
  const ushort_t* pA[2];
  const ushort_t* pB[2];
#pragma unroll
  for (int h = 0; h < 2; h++) {
    int rr = m0 + h * 128 + sr2;
    int rc = (rr < count) ? rr : 0;  // clamp OOB rows to a valid row
    long arow;
    if (PHASE == 1) arow = tok[e * T_TOK + rc];
    else            arow = (long)base[e] + rc;
    pA[h] = Abase + arow * (long)K + kc2 * 8;
    pB[h] = WT + (long)e * ESTRIDE + (long)(n0 + h * 128 + sr2) * K + kc2 * 8;
  }

#define STG(p_, o_)                                                            \
  __builtin_amdgcn_global_load_lds(                                            \
      (const __attribute__((address_space(1))) void*)(p_),                     \
      (__attribute__((address_space(3))) void*)(lds + (o_)), 16, 0, 0)
#define STAGE_A(h_, kt_)                                                       \
  do {                                                                         \
    const ushort_t* s_ = pA[h_] + (long)(kt_) * 64;                            \
    const int d_ = (((kt_) & 1) << 16) + ((h_) << 14) + (w << 10);             \
    STG(s_, d_); STG(s_ + 32, d_ + 8192);                                      \
  } while (0)
#define STAGE_B(h_, kt_)                                                       \
  do {                                                                         \
    const ushort_t* s_ = pB[h_] + (long)(kt_) * 64;                            \
    const int d_ = (((kt_) & 1) << 16) + 32768 + ((h_) << 14) + (w << 10);     \
    STG(s_, d_); STG(s_ + 32, d_ + 8192);                                      \
  } while (0)

#define RD_A(mh_, mq_, kk_)                                                    \
  (*(const bf16x8*)(aB + (kk_) * 8192 + ((mh_) * 64 + (mq_) * 16 + lr) * 64 + swk))
#define RD_B(nh_, nq_, kk_)                                                    \
  (*(const bf16x8*)(bB + (kk_) * 8192 +                                        \
                    ((wn & 1) * 64 + (nh_) * 32 + (nq_) * 16 + lr) * 64 + swk))
#define MFMA(a_, b_, c_) __builtin_amdgcn_mfma_f32_16x16x32_bf16(a_, b_, c_, 0, 0, 0)

  f32x4 acc[8][4] = {};

  // prologue: 6 half-tile stages (12 loads/wave... 2/wave each)
  STAGE_B(0, 0); STAGE_A(0, 0); STAGE_A(1, 0); STAGE_B(1, 0);
  STAGE_B(0, 1); STAGE_A(0, 1);
  asm volatile("s_waitcnt vmcnt(4)" ::: "memory");  // tile 0 resident
  __builtin_amdgcn_s_barrier();
  asm volatile("" ::: "memory");

  for (int t = 0; t < NT; t++) {
    const char* aB = lds + ((t & 1) << 16) + (wm << 14);
    const char* bB = lds + ((t & 1) << 16) + 32768 + ((wn >> 1) << 14);
    bf16x8 av[4][2], bvA[2][2], bvB[2][2];

    // ---- P0: av(mh0), bvA(nh0); stage A1(t+1); MFMA Q(0,0)
#pragma unroll
    for (int mq = 0; mq < 4; mq++) { av[mq][0] = RD_A(0, mq, 0); av[mq][1] = RD_A(0, mq, 1); }
#pragma unroll
    for (int nq = 0; nq < 2; nq++) { bvA[nq][0] = RD_B(0, nq, 0); bvA[nq][1] = RD_B(0, nq, 1); }
    if (t + 1 < NT) STAGE_A(1, t + 1);
    __builtin_amdgcn_s_barrier();
    asm volatile("s_waitcnt lgkmcnt(0)" ::: "memory");
    __builtin_amdgcn_s_setprio(1);
#pragma unroll
    for (int mq = 0; mq < 4; mq++)
#pragma unroll
      for (int nq = 0; nq < 2; nq++) {
        acc[mq][nq] = MFMA(av[mq][0], bvA[nq][0], acc[mq][nq]);
        acc[mq][nq] = MFMA(av[mq][1], bvA[nq][1], acc[mq][nq]);
      }
    __builtin_amdgcn_s_setprio(0);
    __builtin_amdgcn_s_barrier();
    asm volatile("" ::: "memory");

    // ---- P1: bvB(nh1); stage B1(t+1); MFMA Q(0,1)
#pragma unroll
    for (int nq = 0; nq < 2; nq++) { bvB[nq][0] = RD_B(1, nq, 0); bvB[nq][1] = RD_B(1, nq, 1); }
    if (t + 1 < NT) STAGE_B(1, t + 1);
    __builtin_amdgcn_s_barrier();
    asm volatile("s_waitcnt lgkmcnt(0)" ::: "memory");
    __builtin_amdgcn_s_setprio(1);
#pragma unroll
    for (int mq = 0; mq < 4; mq++)
#pragma unroll
      for (int nq = 0; nq < 2; nq++) {
        acc[mq][2 + nq] = MFMA(av[mq][0], bvB[nq][0], acc[mq][2 + nq]);
        acc[mq][2 + nq] = MFMA(av[mq][1], bvB[nq][1], acc[mq][2 + nq]);
      }
    __builtin_amdgcn_s_setprio(0);
    __builtin_amdgcn_s_barrier();
    asm volatile("" ::: "memory");

    // ---- P2: av(mh1); stage B0(t+2); MFMA Q(1,0)
#pragma unroll
    for (int mq = 0; mq < 4; mq++) { av[mq][0] = RD_A(1, mq, 0); av[mq][1] = RD_A(1, mq, 1); }
    if (t + 2 < NT) STAGE_B(0, t + 2);
    __builtin_amdgcn_s_barrier();
    asm volatile("s_waitcnt lgkmcnt(0)" ::: "memory");
    __builtin_amdgcn_s_setprio(1);
#pragma unroll
    for (int mq = 0; mq < 4; mq++)
#pragma unroll
      for (int nq = 0; nq < 2; nq++) {
        acc[4 + mq][nq] = MFMA(av[mq][0], bvA[nq][0], acc[4 + mq][nq]);
        acc[4 + mq][nq] = MFMA(av[mq][1], bvA[nq][1], acc[4 + mq][nq]);
      }
    __builtin_amdgcn_s_setprio(0);
    __builtin_amdgcn_s_barrier();
    asm volatile("" ::: "memory");

    // ---- P3: stage A0(t+2); MFMA Q(1,1); tile boundary
    if (t + 2 < NT) STAGE_A(0, t + 2);
    __builtin_amdgcn_s_barrier();
    asm volatile("s_waitcnt lgkmcnt(0)" ::: "memory");
    __builtin_amdgcn_s_setprio(1);
#pragma unroll
    for (int mq = 0; mq < 4; mq++)
#pragma unroll
      for (int nq = 0; nq < 2; nq++) {
        acc[4 + mq][2 + nq] = MFMA(av[mq][0], bvB[nq][0], acc[4 + mq][2 + nq]);
        acc[4 + mq][2 + nq] = MFMA(av[mq][1], bvB[nq][1], acc[4 + mq][2 + nq]);
      }
    __builtin_amdgcn_s_setprio(0);
    if (t == NT - 2) asm volatile("s_waitcnt vmcnt(0)" ::: "memory");
    else             asm volatile("s_waitcnt vmcnt(4)" ::: "memory");
    __builtin_amdgcn_s_barrier();
    asm volatile("" ::: "memory");
  }
#undef STG
#undef STAGE_A
#undef STAGE_B
#undef RD_A
#undef RD_B
#undef MFMA

  const float* bias = (e == NE) ? bias_s : (bias_e + (long)e * N);
#pragma unroll
  for (int m = 0; m < 8; m++) {
#pragma unroll
    for (int j = 0; j < 4; j++) {
      int rloc = wm * 128 + m * 16 + lg * 4 + j;  // D row = (lane>>4)*4 + reg
      int rr = m0 + rloc;
      if (rr >= count) continue;
      if (PHASE == 1) {
        long orow = (long)base[e] + rr;
#pragma unroll
        for (int n = 0; n < 4; n++) {
          int col = n0 + wn * 64 + n * 16 + lr;  // D col = lane&15
          float v = acc[m][n][j] + bias[col];
          He[orow * FF_DIM + col] = f2bf(gelu_f(v));
        }
      } else {
        int tt = tok[e * T_TOK + rr];
        if (e == NE) {  // shared FFN -> write d_out directly
#pragma unroll
          for (int n = 0; n < 4; n++) {
            int col = n0 + wn * 64 + n * 16 + lr;
            out[(long)tt * D_DIM + col] = acc[m][n][j] + bias[col];
          }
        } else {
          float wgt = wof[e * T_TOK + rr];
          int rk = rankof[e * T_TOK + rr];
          float* dst = ybuf + (long)rk * ((long)T_TOK * D_DIM) + (long)tt * D_DIM;
#pragma unroll
          for (int n = 0; n < 4; n++) {
            int col = n0 + wn * 64 + n * 16 + lr;
            dst[col] = wgt * (acc[m][n][j] + bias[col]);
          }
        }
      }
    }
  }
}

// ---------------- final: out += y_rank0 + y_rank1 ---------------------------
__global__ void final_add_kernel(float* __restrict__ out, const float* __restrict__ ybuf) {
  long i = ((long)blockIdx.x * 256 + threadIdx.x) * 4;
  float4 a = *(const float4*)(out + i);
  float4 b = *(const float4*)(ybuf + i);
  float4 c = *(const float4*)(ybuf + (long)T_TOK * D_DIM + i);
  a.x += b.x + c.x; a.y += b.y + c.y; a.z += b.z + c.z; a.w += b.w + c.w;
  *(float4*)(out + i) = a;
}

extern "C" void kernel_launch(void* const* d_in, const int* in_sizes, int n_in,
                              void* d_out, int out_size, void* d_ws, size_t ws_size,
                              hipStream_t stream) {
  (void)in_sizes; (void)n_in; (void)out_size; (void)ws_size;
  const float* x   = (const float*)d_in[0];
  const float* Wg  = (const float*)d_in[1];
  const float* W1  = (const float*)d_in[2];
  const float* b1  = (const float*)d_in[3];
  const float* W2  = (const float*)d_in[4];
  const float* b2  = (const float*)d_in[5];
  const float* Ws1 = (const float*)d_in[6];
  const float* bs1 = (const float*)d_in[7];
  const float* Ws2 = (const float*)d_in[8];
  const float* bs2 = (const float*)d_in[9];
  float* out = (float*)d_out;

  char* ws = (char*)d_ws;
  int*      cnt    = (int*)(ws + 0);
  int*      base   = (int*)(ws + 64);
  int*      tok    = (int*)(ws + 256);
  float*    wof    = (float*)(ws + 256 + 147456);
  int*      rankof = (int*)(ws + 256 + 2 * 147456);
  ushort_t* Xbf    = (ushort_t*)(ws + 442624);
  ushort_t* W1T    = (ushort_t*)(ws + 8831232);
  ushort_t* W2T    = (ushort_t*)(ws + 84328704);
  ushort_t* He     = (ushort_t*)(ws + 159826176);
  float*    ybuf   = (float*)(ws + 261538048);

  hipMemsetAsync(cnt, 0, 64, stream);
  gate_kernel<<<T_TOK, 64, 0, stream>>>(x, Wg, cnt, tok, wof, rankof);
  scan_kernel<<<1, 64, 0, stream>>>(cnt, base);
  cvt_x_kernel<<<2048, 256, 0, stream>>>(x, Xbf);
  tcvt_kernel<<<dim3(64, 16, 8), 256, 0, stream>>>(W1, W1T, 1024, 4096);
  tcvt_kernel<<<dim3(16, 64, 8), 256, 0, stream>>>(W2, W2T, 4096, 1024);
  tcvt_kernel<<<dim3(64, 16, 1), 256, 0, stream>>>(Ws1, W1T + 8L * ESTRIDE, 1024, 4096);
  tcvt_kernel<<<dim3(16, 64, 1), 256, 0, stream>>>(Ws2, W2T + 8L * ESTRIDE, 4096, 1024);
  gemm_kernel<1024, 4096, 1><<<dim3(16, 16, 9), 512, 0, stream>>>(
      Xbf, W1T, b1, bs1, cnt, base, tok, wof, rankof, He, ybuf, out);
  gemm_kernel<4096, 1024, 2><<<dim3(4, 16, 9), 512, 0, stream>>>(
      He, W2T, b2, bs2, cnt, base, tok, wof, rankof, He, ybuf, out);
  final_add_kernel<<<4096, 256, 0, stream>>>(out, ybuf);
}